// Round 9
// baseline (266.278 us; speedup 1.0000x reference)
//
#include <hip/hip_runtime.h>
#include <hip/hip_bf16.h>
#include <cstdint>

#define DI __device__ __forceinline__

typedef short bf16x8 __attribute__((ext_vector_type(8)));
typedef float f32x4 __attribute__((ext_vector_type(4)));
typedef unsigned short u16;
typedef unsigned short u16x8 __attribute__((ext_vector_type(8)));

static constexpr int NV = 10, NE = 90, TT = 64;
static constexpr int R1 = 20480;   // 32*10*64 node rows
static constexpr int R2 = 184320;  // 32*90*64 edge rows

DI float bf2f(u16 u) { union { unsigned int i; float f; } x; x.i = ((unsigned int)u) << 16; return x.f; }
DI u16 f2bf(float f) { unsigned int u = __float_as_uint(f); return (u16)((u + 0x7FFF + ((u >> 16) & 1)) >> 16); }
DI float elu(float v) { return v > 0.f ? v : __expf(v) - 1.f; }

#define GLL(srcp, dstp) __builtin_amdgcn_global_load_lds( \
    (const __attribute__((address_space(1))) unsigned int*)(srcp), \
    (__attribute__((address_space(3))) unsigned int*)(dstp), 16, 0, 0)

// ============================================================================
// Weight tile-packing (128-tile engine): PK[(bn*8+kt)*2+p][tid] u16x8 holds
//   w[k = kt*32+(tid&3)*8+e][n = bn*128 + p*64 + (tid>>2)]
// ============================================================================
__global__ __launch_bounds__(256) void pack4(
    const float* __restrict__ s0, u16* __restrict__ d0,
    const float* __restrict__ s1, u16* __restrict__ d1,
    const float* __restrict__ s2, u16* __restrict__ d2,
    const float* __restrict__ s3, u16* __restrict__ d3) {
    const float* s; u16* d;
    switch (blockIdx.y) {
        case 0: s = s0; d = d0; break;
        case 1: s = s1; d = d1; break;
        case 2: s = s2; d = d2; break;
        default: s = s3; d = d3; break;
    }
    int tid = threadIdx.x;
    int bn = blockIdx.x >> 3, kt = blockIdx.x & 7;
#pragma unroll
    for (int p = 0; p < 2; ++p) {
        int n = bn * 128 + p * 64 + (tid >> 2);
        int k = kt * 32 + (tid & 3) * 8;
        u16x8 pk;
#pragma unroll
        for (int e = 0; e < 8; ++e) pk[e] = f2bf(s[(size_t)(k + e) * 256 + n]);
        *(u16x8*)(d + ((size_t)((bn * 8 + kt) * 2 + p)) * 2048 + (size_t)tid * 8) = pk;
    }
}

// ============================================================================
// 256-tile packs: PK[kt*2+p][tid2 in 0..511] u16x8 holds
//   w[k = kt*32+(tid2&3)*8+e][n = p*128 + (tid2>>2)]
// ============================================================================
__global__ __launch_bounds__(256) void pack256(const float* __restrict__ s,
                                               u16* __restrict__ d) {
    int kt = blockIdx.x;
#pragma unroll
    for (int h = 0; h < 2; ++h) {
        int tid2 = threadIdx.x + h * 256;
#pragma unroll
        for (int p = 0; p < 2; ++p) {
            int n = p * 128 + (tid2 >> 2);
            int k = kt * 32 + (tid2 & 3) * 8;
            u16x8 pk;
#pragma unroll
            for (int e = 0; e < 8; ++e) pk[e] = f2bf(s[(size_t)(k + e) * 256 + n]);
            *(u16x8*)(d + ((size_t)(kt * 2 + p)) * 4096 + (size_t)tid2 * 8) = pk;
        }
    }
}

// w2a 256-tile pack, K=512, BN1 scale folded
__global__ __launch_bounds__(256) void pack256_w2a(const float* __restrict__ w2a,
                                                   const float* __restrict__ scsh1,
                                                   u16* __restrict__ d) {
    int kt = blockIdx.x;
#pragma unroll
    for (int h = 0; h < 2; ++h) {
        int tid2 = threadIdx.x + h * 256;
#pragma unroll
        for (int p = 0; p < 2; ++p) {
            int n = p * 128 + (tid2 >> 2);
            int k = kt * 32 + (tid2 & 3) * 8;
            u16x8 pk;
#pragma unroll
            for (int e = 0; e < 8; ++e)
                pk[e] = f2bf(scsh1[(k + e) & 255] * w2a[(size_t)(k + e) * 256 + n]);
            *(u16x8*)(d + ((size_t)(kt * 2 + p)) * 4096 + (size_t)tid2 * 8) = pk;
        }
    }
}

__global__ void zero_stats(float* p, int n) {
    int i = blockIdx.x * 256 + threadIdx.x;
    if (i < n) p[i] = 0.f;
}

__global__ void conv_wo2(const float* __restrict__ src, u16* __restrict__ dst) {
    dst[threadIdx.x] = f2bf(src[threadIdx.x]);
}

// BN1 shift term folded into fc1 bias
__global__ __launch_bounds__(256) void fold_b2a(const float* __restrict__ w2a,
                                                const float* __restrict__ scsh1,
                                                const float* __restrict__ b2a,
                                                float* __restrict__ b2aF) {
    __shared__ float red[256];
    int n = blockIdx.x, tid = threadIdx.x;
    float sc = scsh1[256 + tid];
    float s = sc * w2a[tid * 256 + n] + sc * w2a[(tid + 256) * 256 + n];
    red[tid] = s;
    __syncthreads();
    for (int off2 = 128; off2 > 0; off2 >>= 1) {
        if (tid < off2) red[tid] += red[tid + off2];
        __syncthreads();
    }
    if (tid == 0) b2aF[n] = red[0] + b2a[n];
}

__global__ void stats_final(const float* __restrict__ sums, const float* __restrict__ g,
                            const float* __restrict__ be, float invR, float* __restrict__ scsh) {
    int c = threadIdx.x;
    float mu = sums[c] * invR;
    float var = sums[256 + c] * invR - mu * mu;
    float rs = rsqrtf(var + 1e-5f);
    float sc = g[c] * rs;
    scsh[c] = sc;
    scsh[256 + c] = be[c] - mu * sc;
}

// -------------------- mlp1 fc1: K=4, VALU (verified) -------------------------
__global__ __launch_bounds__(256) void mlp1_fc1(const float* __restrict__ x,
                                                const float* __restrict__ w1a,
                                                const float* __restrict__ b1a,
                                                u16* __restrict__ ha) {
    int tid = threadIdx.x;
    int row = blockIdx.x * 8 + (tid >> 5);
    int ch8 = (tid & 31) * 8;
    int b = row / (NV * TT);
    int v = (row >> 6) % NV;
    int t = row & 63;
    const float* xp = x + ((size_t)(b * TT + t) * NV + v) * 4;
    float x0 = xp[0], x1 = xp[1], x2 = xp[2], x3 = xp[3];
    u16x8 pack;
#pragma unroll
    for (int e = 0; e < 8; ++e) {
        int c = ch8 + e;
        float acc = b1a[c] + x0 * w1a[c] + x1 * w1a[256 + c] + x2 * w1a[512 + c] + x3 * w1a[768 + c];
        pack[e] = f2bf(elu(acc));
    }
    *(u16x8*)(ha + (size_t)row * 256 + ch8) = pack;
}

// ============================================================================
// 128x128 engine (r7/r8 verified, packed-B) — used for the R1 GEMMs.
// ============================================================================
template <int ACT, bool STATS>   // ACT: 1 elu, 2 relu
__global__ __launch_bounds__(256) void gemm_kernel(const u16* __restrict__ A,
                                                   const u16* __restrict__ Wt,
                                                   const float* __restrict__ bias,
                                                   u16* __restrict__ out,
                                                   int K,
                                                   float* __restrict__ stats) {
    __shared__ u16 As[3][128 * 32];
    __shared__ u16 Bs[3][128 * 32];
    const int tid = threadIdx.x;
    const int lane = tid & 63, wid = tid >> 6;

    int bm, bn;
    {
        int bid = blockIdx.x;
        int xcd = bid & 7, slot = bid >> 3;
        bn = slot & 1;
        bm = xcd + 8 * (slot >> 1);
    }
    const int m0 = bm * 128, n0 = bn * 128;
    const int wm = wid >> 1, wn = wid & 1;

    const int srow = tid >> 2;
    const int scol8 = (tid & 3) * 8;

    size_t abase0 = (size_t)(m0 + srow) * K;
    size_t abase1 = (size_t)(m0 + srow + 64) * K;
    const int NT = K >> 5;
    const size_t bnbase = (size_t)bn * NT * 4096;

    f32x4 acc[4][4];
#pragma unroll
    for (int i = 0; i < 4; ++i)
#pragma unroll
        for (int j = 0; j < 4; ++j) acc[i][j] = (f32x4)0.f;

    const int lrow = lane & 15;
    const int lk8 = (lane >> 4) * 8;

    auto stage = [&](int bf, int k0) {
        const size_t btile = bnbase + (size_t)(k0 >> 5) * 4096 + (size_t)tid * 8;
        GLL(A + abase0 + k0 + scol8, &As[bf][(wid * 64) * 8]);
        GLL(Wt + btile, &Bs[bf][(wid * 64) * 8]);
        GLL(A + abase1 + k0 + scol8, &As[bf][(256 + wid * 64) * 8]);
        GLL(Wt + btile + 2048, &Bs[bf][(256 + wid * 64) * 8]);
    };

    stage(0, 0);
    stage(1, 32);
    for (int kt = 0; kt < NT; ++kt) {
        if (kt + 1 < NT) {
            asm volatile("s_waitcnt vmcnt(4)" ::: "memory");
        } else {
            asm volatile("s_waitcnt vmcnt(0)" ::: "memory");
        }
        __builtin_amdgcn_s_barrier();
        if (kt + 2 < NT) stage((kt + 2) % 3, (kt + 2) * 32);
        __builtin_amdgcn_sched_barrier(0);
        const int buf = kt % 3;
        bf16x8 a[4], b[4];
#pragma unroll
        for (int i = 0; i < 4; ++i)
            a[i] = *(const bf16x8*)&As[buf][(wm * 64 + i * 16 + lrow) * 32 + lk8];
#pragma unroll
        for (int j = 0; j < 4; ++j)
            b[j] = *(const bf16x8*)&Bs[buf][(wn * 64 + j * 16 + lrow) * 32 + lk8];
#pragma unroll
        for (int i = 0; i < 4; ++i)
#pragma unroll
            for (int j = 0; j < 4; ++j)
                acc[i][j] = __builtin_amdgcn_mfma_f32_16x16x32_bf16(a[i], b[j], acc[i][j], 0, 0, 0);
    }

    float bv[4], sv[4], qv[4];
#pragma unroll
    for (int j = 0; j < 4; ++j) {
        bv[j] = bias[n0 + wn * 64 + j * 16 + lrow];
        if constexpr (STATS) { sv[j] = 0.f; qv[j] = 0.f; }
    }
#pragma unroll
    for (int i = 0; i < 4; ++i) {
#pragma unroll
        for (int j = 0; j < 4; ++j) {
            int col = n0 + wn * 64 + j * 16 + lrow;
#pragma unroll
            for (int r = 0; r < 4; ++r) {
                int row = m0 + wm * 64 + i * 16 + (lane >> 4) * 4 + r;
                float v = acc[i][j][r] + bv[j];
                v = (ACT == 1) ? elu(v) : (v > 0.f ? v : 0.f);
                if constexpr (STATS) { sv[j] += v; qv[j] += v * v; }
                out[(size_t)row * 256 + col] = f2bf(v);
            }
        }
    }
    if constexpr (STATS) {
#pragma unroll
        for (int j = 0; j < 4; ++j) {
            float s = sv[j], q_ = qv[j];
            s += __shfl_xor(s, 16); q_ += __shfl_xor(q_, 16);
            s += __shfl_xor(s, 32); q_ += __shfl_xor(q_, 32);
            if ((lane >> 4) == 0) {
                int col = n0 + wn * 64 + j * 16 + lrow;
                atomicAdd(&stats[col], s);
                atomicAdd(&stats[256 + col], q_);
            }
        }
    }
}

// ============================================================================
// 256x256 engine for the two R2 GEMMs: same 3-buf counted-vmcnt pipeline,
// 512 threads / 8 waves (2M x 4N), wave tile 128x64 (acc[8][4]).
// Staged bytes per output element HALVED vs 128x128 (A staged once: BN=N=256;
// B staged 720x instead of 1440x).  Per-thread GLLs per stage = 4 (as r7/r8),
// so the vmcnt(4) retire-my-tile constant is unchanged.
// Block->XCD: chunked (90 consecutive bm per XCD; 720 = 8*90 bijective).
// ============================================================================
template <bool GATHER, bool STATS>
__global__ __launch_bounds__(512) void gemm256(const u16* __restrict__ A,
                                               const u16* __restrict__ PK,
                                               const float* __restrict__ bias,
                                               u16* __restrict__ out,
                                               int K,
                                               float* __restrict__ stats) {
    __shared__ u16 As[3][256 * 32];   // 48 KB
    __shared__ u16 Bs[3][256 * 32];   // 48 KB
    const int tid = threadIdx.x;
    const int lane = tid & 63, wid = tid >> 6;   // wid 0..7

    const int bm = (blockIdx.x & 7) * 90 + (blockIdx.x >> 3);  // chunked XCD map
    const int m0 = bm * 256;
    const int wm = wid >> 2, wn = wid & 3;       // 2 x 4 wave grid

    const int srow = tid >> 2;                   // 0..127
    const int scol8 = (tid & 3) * 8;

    size_t ab0 = 0, ab1 = 0, sb0 = 0, sb1 = 0, rb0 = 0, rb1 = 0;
    if constexpr (GATHER) {
        {
            int m = m0 + srow;
            int t = m & 63, be = m >> 6, e = be % NE, b = be / NE;
            int s = e / 9, kk = e - s * 9, r = kk + (kk >= s ? 1 : 0);
            sb0 = ((size_t)((b * NV + s) * TT + t)) * 256;
            rb0 = ((size_t)((b * NV + r) * TT + t)) * 256;
        }
        {
            int m = m0 + srow + 128;
            int t = m & 63, be = m >> 6, e = be % NE, b = be / NE;
            int s = e / 9, kk = e - s * 9, r = kk + (kk >= s ? 1 : 0);
            sb1 = ((size_t)((b * NV + s) * TT + t)) * 256;
            rb1 = ((size_t)((b * NV + r) * TT + t)) * 256;
        }
    } else {
        ab0 = (size_t)(m0 + srow) * K;
        ab1 = (size_t)(m0 + srow + 128) * K;
    }
    const int NT = K >> 5;

    f32x4 acc[8][4];
#pragma unroll
    for (int i = 0; i < 8; ++i)
#pragma unroll
        for (int j = 0; j < 4; ++j) acc[i][j] = (f32x4)0.f;

    const int lrow = lane & 15;
    const int lk8 = (lane >> 4) * 8;

    auto stage = [&](int bf, int k0) {
        const size_t btile = (size_t)(k0 >> 5) * 8192 + (size_t)tid * 8;
        const u16 *a0, *a1;
        if constexpr (GATHER) {
            int f = k0 + scol8;
            a0 = A + (f < 256 ? sb0 + f : rb0 + (f - 256));
            a1 = A + (f < 256 ? sb1 + f : rb1 + (f - 256));
        } else {
            a0 = A + ab0 + k0 + scol8;
            a1 = A + ab1 + k0 + scol8;
        }
        GLL(a0, &As[bf][tid * 8]);
        GLL(PK + btile, &Bs[bf][tid * 8]);
        GLL(a1, &As[bf][4096 + tid * 8]);
        GLL(PK + btile + 4096, &Bs[bf][4096 + tid * 8]);
    };

    stage(0, 0);
    stage(1, 32);
    for (int kt = 0; kt < NT; ++kt) {
        if (kt + 1 < NT) {
            asm volatile("s_waitcnt vmcnt(4)" ::: "memory");
        } else {
            asm volatile("s_waitcnt vmcnt(0)" ::: "memory");
        }
        __builtin_amdgcn_s_barrier();
        if (kt + 2 < NT) stage((kt + 2) % 3, (kt + 2) * 32);
        __builtin_amdgcn_sched_barrier(0);
        const int buf = kt % 3;
        bf16x8 a[8], b[4];
#pragma unroll
        for (int i = 0; i < 8; ++i)
            a[i] = *(const bf16x8*)&As[buf][(wm * 128 + i * 16 + lrow) * 32 + lk8];
#pragma unroll
        for (int j = 0; j < 4; ++j)
            b[j] = *(const bf16x8*)&Bs[buf][(wn * 64 + j * 16 + lrow) * 32 + lk8];
#pragma unroll
        for (int i = 0; i < 8; ++i)
#pragma unroll
            for (int j = 0; j < 4; ++j)
                acc[i][j] = __builtin_amdgcn_mfma_f32_16x16x32_bf16(a[i], b[j], acc[i][j], 0, 0, 0);
    }

    float bv[4], sv[4], qv[4];
#pragma unroll
    for (int j = 0; j < 4; ++j) {
        bv[j] = bias[wn * 64 + j * 16 + lrow];
        if constexpr (STATS) { sv[j] = 0.f; qv[j] = 0.f; }
    }
#pragma unroll
    for (int i = 0; i < 8; ++i) {
#pragma unroll
        for (int j = 0; j < 4; ++j) {
            int col = wn * 64 + j * 16 + lrow;
#pragma unroll
            for (int r = 0; r < 4; ++r) {
                int row = m0 + wm * 128 + i * 16 + (lane >> 4) * 4 + r;
                float v = acc[i][j][r] + bv[j];
                v = elu(v);
                if constexpr (STATS) { sv[j] += v; qv[j] += v * v; }
                out[(size_t)row * 256 + col] = f2bf(v);
            }
        }
    }
    if constexpr (STATS) {
#pragma unroll
        for (int j = 0; j < 4; ++j) {
            float s = sv[j], q_ = qv[j];
            s += __shfl_xor(s, 16); q_ += __shfl_xor(q_, 16);
            s += __shfl_xor(s, 32); q_ += __shfl_xor(q_, 32);
            if ((lane >> 4) == 0) {
                int col = wn * 64 + j * 16 + lrow;
                atomicAdd(&stats[col], s);
                atomicAdd(&stats[256 + col], q_);
            }
        }
    }
}

// -------------------- elementwise affine + relu (BN3) ------------------------
__global__ __launch_bounds__(256) void norm_affine_relu(const u16* __restrict__ in,
                                                        const float* __restrict__ scsh,
                                                        u16* __restrict__ out, int n8) {
    int i = blockIdx.x * 256 + threadIdx.x;
    if (i >= n8) return;
    size_t base = (size_t)i * 8;
    int ch8 = (int)(base & 255);
    u16x8 v = *(const u16x8*)(in + base);
    u16x8 o;
#pragma unroll
    for (int e = 0; e < 8; ++e) {
        float f = bf2f(v[e]);
        f = scsh[ch8 + e] * f + scsh[256 + ch8 + e];
        o[e] = f2bf(f > 0.f ? f : 0.f);
    }
    *(u16x8*)(out + base) = o;
}

// -------------------- edge2node: incidence sum + BN2 affine (verified) -------
__global__ __launch_bounds__(256) void edge2node(const u16* __restrict__ h2,
                                                 const float* __restrict__ scsh2,
                                                 u16* __restrict__ n1) {
    int tid = threadIdx.x;
    int row = blockIdx.x * 8 + (tid >> 5);
    int ch8 = (tid & 31) * 8;
    int t = row & 63;
    int bv = row >> 6;
    int v = bv % NV;
    int b = bv / NV;
    float acc[8] = {0, 0, 0, 0, 0, 0, 0, 0};
#pragma unroll
    for (int i = 0; i < 9; ++i) {
        int s = i + (i >= v ? 1 : 0);
        int e = s * 9 + (v < s ? v : v - 1);
        u16x8 vv = *(const u16x8*)(h2 + ((size_t)((b * NE + e) * TT + t)) * 256 + ch8);
#pragma unroll
        for (int k = 0; k < 8; ++k) acc[k] += bf2f(vv[k]);
    }
    const float inv9 = 1.f / 9.f;
    u16x8 o;
#pragma unroll
    for (int k = 0; k < 8; ++k) {
        int c = ch8 + k;
        o[k] = f2bf(scsh2[c] * (acc[k] * inv9) + scsh2[256 + c]);
    }
    *(u16x8*)(n1 + (size_t)row * 256 + ch8) = o;
}

// -------------------- final head: dot(a2_row, wo2) + bo2 (verified) ----------
__global__ __launch_bounds__(256) void head2(const u16* __restrict__ a2,
                                             const u16* __restrict__ wo2t,
                                             const float* __restrict__ bo2,
                                             float* __restrict__ out) {
    int tid = threadIdx.x;
    int row = blockIdx.x * 8 + (tid >> 5);
    int l32 = tid & 31;
    int ch8 = l32 * 8;
    u16x8 a = *(const u16x8*)(a2 + (size_t)row * 256 + ch8);
    u16x8 w = *(const u16x8*)(wo2t + ch8);
    float p = 0.f;
#pragma unroll
    for (int k = 0; k < 8; ++k) p += bf2f(a[k]) * bf2f(w[k]);
#pragma unroll
    for (int off = 16; off > 0; off >>= 1) p += __shfl_down(p, off, 32);
    if (l32 == 0) {
        int b = row / (NV * TT);
        int v = (row >> 6) % NV;
        int t = row & 63;
        out[(size_t)(b * TT + t) * NV + v] = p + bo2[0];
    }
}

extern "C" void kernel_launch(void* const* d_in, const int* in_sizes, int n_in,
                              void* d_out, int out_size, void* d_ws, size_t ws_size,
                              hipStream_t stream) {
    const float* x   = (const float*)d_in[0];
    const float* w1a = (const float*)d_in[1];
    const float* b1a = (const float*)d_in[2];
    const float* w1b = (const float*)d_in[3];
    const float* b1b = (const float*)d_in[4];
    const float* g1  = (const float*)d_in[5];
    const float* be1 = (const float*)d_in[6];
    const float* w2a = (const float*)d_in[7];
    const float* b2a = (const float*)d_in[8];
    const float* w2b = (const float*)d_in[9];
    const float* b2b = (const float*)d_in[10];
    const float* g2  = (const float*)d_in[11];
    const float* be2 = (const float*)d_in[12];
    const float* w3a = (const float*)d_in[13];
    const float* b3a = (const float*)d_in[14];
    const float* w3b = (const float*)d_in[15];
    const float* b3b = (const float*)d_in[16];
    const float* g3  = (const float*)d_in[17];
    const float* be3 = (const float*)d_in[18];
    const float* wo1 = (const float*)d_in[19];
    const float* bo1 = (const float*)d_in[20];
    const float* wo2 = (const float*)d_in[21];
    const float* bo2 = (const float*)d_in[22];
    float* out = (float*)d_out;

    char* ws = (char*)d_ws;
    size_t off = 0;
    auto alloc = [&](size_t bytes) {
        void* p = ws + off;
        off = (off + bytes + 255) & ~(size_t)255;
        return p;
    };
    u16* w1bP = (u16*)alloc(2 * 8 * 4096 * 2);     // 128-tile pack, K=256
    u16* w3aP = (u16*)alloc(2 * 8 * 4096 * 2);
    u16* w3bP = (u16*)alloc(2 * 8 * 4096 * 2);
    u16* wo1P = (u16*)alloc(2 * 8 * 4096 * 2);
    u16* w2aP = (u16*)alloc(16 * 8192 * 2);        // 256-tile pack, K=512 (folded)
    u16* w2bP = (u16*)alloc(8 * 8192 * 2);         // 256-tile pack, K=256
    u16* wo2T = (u16*)alloc(256 * 2);
    float* sums  = (float*)alloc(3 * 512 * 4);
    float* scsh1 = (float*)alloc(512 * 4);
    float* scsh2 = (float*)alloc(512 * 4);
    float* scsh3 = (float*)alloc(512 * 4);
    float* b2aF  = (float*)alloc(256 * 4);
    u16* S0 = (u16*)alloc((size_t)R1 * 256 * 2);
    u16* S1 = (u16*)alloc((size_t)R1 * 256 * 2);
    u16* S2 = (u16*)alloc((size_t)R1 * 256 * 2);
    u16* BIG1 = (u16*)alloc((size_t)R2 * 256 * 2);
    u16* BIG2 = (u16*)alloc((size_t)R2 * 256 * 2);

    dim3 pgrid(16, 4);
    pack4<<<pgrid, 256, 0, stream>>>(w1b, w1bP, w3a, w3aP, w3b, w3bP, wo1, wo1P);
    pack256<<<8, 256, 0, stream>>>(w2b, w2bP);
    zero_stats<<<6, 256, 0, stream>>>(sums, 3 * 512);
    conv_wo2<<<1, 256, 0, stream>>>(wo2, wo2T);

    // mlp1: fc1 (VALU) + fc2 GEMM with fused stats
    mlp1_fc1<<<R1 / 8, 256, 0, stream>>>(x, w1a, b1a, S0);
    gemm_kernel<1, true><<<(R1 / 128) * 2, 256, 0, stream>>>(S0, w1bP, b1b, S1, 256, sums);
    stats_final<<<1, 256, 0, stream>>>(sums, g1, be1, 1.f / R1, scsh1);
    pack256_w2a<<<16, 256, 0, stream>>>(w2a, scsh1, w2aP);
    fold_b2a<<<256, 256, 0, stream>>>(w2a, scsh1, b2a, b2aF);

    // mlp2: 256x256 tiles — gather fc1 (BN1 folded), fc2 with fused stats
    gemm256<true, false><<<R2 / 256, 512, 0, stream>>>(S1, w2aP, b2aF, BIG1, 512, nullptr);
    gemm256<false, true><<<R2 / 256, 512, 0, stream>>>(BIG1, w2bP, b2b, BIG2, 256, sums + 512);
    stats_final<<<1, 256, 0, stream>>>(sums + 512, g2, be2, 1.f / R2, scsh2);

    // edge2node (BN2 affine folded in)
    edge2node<<<R1 / 8, 256, 0, stream>>>(BIG2, scsh2, S0);

    // mlp3: two GEMMs, stats fused into fc2
    gemm_kernel<1, false><<<(R1 / 128) * 2, 256, 0, stream>>>(S0, w3aP, b3a, S1, 256, nullptr);
    gemm_kernel<1, true><<<(R1 / 128) * 2, 256, 0, stream>>>(S1, w3bP, b3b, S2, 256, sums + 1024);
    stats_final<<<1, 256, 0, stream>>>(sums + 1024, g3, be3, 1.f / R1, scsh3);

    // head: BN3 affine+relu, wo1 GEMM (relu), dot wo2
    norm_affine_relu<<<(R1 * 32 + 255) / 256, 256, 0, stream>>>(S2, scsh3, S0, R1 * 32);
    gemm_kernel<2, false><<<(R1 / 128) * 2, 256, 0, stream>>>(S0, wo1P, bo1, S1, 256, nullptr);
    head2<<<R1 / 8, 256, 0, stream>>>(S1, wo2T, bo2, out);
}